// Round 9
// baseline (1011.853 us; speedup 1.0000x reference)
//
#include <hip/hip_runtime.h>
#include <cstddef>

// ---------------- weight prep: conv1 w (32,3,11,11) -> wT1 [r=ic*11+kh][oc][12]
__global__ __launch_bounds__(256) void prep_w1(const float* __restrict__ w,
                                               float* __restrict__ wT) {
  const int j = blockIdx.x * 256 + threadIdx.x;
  if (j >= 33 * 32 * 12) return;
  const int kw = j % 12, oc = (j / 12) % 32, r = j / (12 * 32);
  wT[j] = (kw < 11) ? w[oc * 363 + r * 11 + kw] : 0.f;
}

// ---------------- weight prep: conv2 w (16,32,9,9) -> wT2 [ic][kh][oc][12]
__global__ __launch_bounds__(256) void prep_w2(const float* __restrict__ w,
                                               float* __restrict__ wT) {
  const int j = blockIdx.x * 256 + threadIdx.x;
  if (j >= 32 * 9 * 16 * 12) return;
  const int kw = j % 12, oc = (j / 12) % 16;
  const int kh = (j / 192) % 9, ic = j / 1728;
  wT[j] = (kw < 9) ? w[(size_t)oc * 2592 + ic * 81 + kh * 9 + kw] : 0.f;
}

// ---------------- conv1 v4: weights direct from global wT1 (broadcast, L2-hot);
// LDS holds only the x tile (13.7 KB) -> ~5 blocks/CU.
__global__ __launch_bounds__(256, 4) void conv1_v4(const float* __restrict__ x,
                                                   const float* __restrict__ wT,
                                                   const float* __restrict__ bias,
                                                   float* __restrict__ out) {
  __shared__ __align__(16) float xs[3][26][44];
  const int wt = blockIdx.x, ht = blockIdx.y, b = blockIdx.z;
  const int tid = threadIdx.x;
  const int posg = tid & 31;
  const int ocg = tid >> 5;
  const int owg = posg & 1;
  const int ohl = posg >> 1;
  const int ih0 = ht * 16, iw0 = wt * 32;

  for (int j = tid; j < 3 * 26 * 42; j += 256) {
    const int ic = j / 1092, r = (j % 1092) / 42, c = j % 42;
    const int ih = min(ih0 + r, 151), iw = min(iw0 + c, 151);
    xs[ic][r][c] = x[((size_t)b * 3 + ic) * 23104 + ih * 152 + iw];
  }
  __syncthreads();

  const int oh = ih0 + ohl;
  if (oh >= 142) return;
  float acc[4][16] = {};
  for (int ic = 0; ic < 3; ++ic) {
    for (int kh = 0; kh < 11; ++kh) {
      const int r = ic * 11 + kh;
      float xv[28];
      const float* xr = &xs[ic][ohl + kh][owg * 16];
      #pragma unroll
      for (int j = 0; j < 7; ++j) *(float4*)&xv[4 * j] = *(const float4*)&xr[4 * j];
      float wv[4][12];
      #pragma unroll
      for (int o = 0; o < 4; ++o) {
        const float* wr = &wT[(r * 32 + ocg * 4 + o) * 12];
        *(float4*)&wv[o][0] = *(const float4*)&wr[0];
        *(float4*)&wv[o][4] = *(const float4*)&wr[4];
        *(float4*)&wv[o][8] = *(const float4*)&wr[8];
      }
      #pragma unroll
      for (int kw = 0; kw < 11; ++kw)
        #pragma unroll
        for (int o = 0; o < 4; ++o)
          #pragma unroll
          for (int p = 0; p < 16; ++p)
            acc[o][p] += xv[kw + p] * wv[o][kw];
    }
  }

  const int ow0 = iw0 + owg * 16;
  #pragma unroll
  for (int o = 0; o < 4; ++o) {
    const int oc = ocg * 4 + o;
    const float bv = bias[oc];
    float* op = &out[(((size_t)b * 32 + oc) * 142 + oh) * 142 + ow0];
    if (ow0 + 16 <= 142) {
      #pragma unroll
      for (int p = 0; p < 16; p += 2) {
        float2 rv;
        rv.x = fmaxf(acc[o][p] + bv, 0.f);
        rv.y = fmaxf(acc[o][p + 1] + bv, 0.f);
        *(float2*)&op[p] = rv;
      }
    } else {
      for (int p = 0; p < 16; ++p)
        if (ow0 + p < 142) op[p] = fmaxf(acc[o][p] + bv, 0.f);
    }
  }
}

// ---------------- maxpool 3x3 s2 p1
__global__ __launch_bounds__(256) void pool_3_2_1(const float* __restrict__ in,
                                                  float* __restrict__ out) {
  const int idx = blockIdx.x * 256 + threadIdx.x;
  const int total = 32 * 32 * 71 * 71;
  if (idx >= total) return;
  const int ow = idx % 71;
  const int oh = (idx / 71) % 71;
  const int bc = idx / (71 * 71);
  const float* base = in + (size_t)bc * 142 * 142;
  float m = -1e30f;
  #pragma unroll
  for (int kh = 0; kh < 3; ++kh) {
    const int ih = oh * 2 - 1 + kh;
    if (ih < 0 || ih >= 142) continue;
    #pragma unroll
    for (int kw = 0; kw < 3; ++kw) {
      const int iw = ow * 2 - 1 + kw;
      if (iw < 0 || iw >= 142) continue;
      m = fmaxf(m, base[ih * 142 + iw]);
    }
  }
  out[idx] = m;
}

// ---------------- conv2: ic-split x4 partials; weights direct from global wT2.
__global__ __launch_bounds__(128, 4) void conv2_part(const float* __restrict__ x,
                                                     const float* __restrict__ wT,
                                                     float* __restrict__ part) {
  __shared__ __align__(16) float xs[2][24][44];
  const int wt = blockIdx.x, ht = blockIdx.y;
  const int b = blockIdx.z >> 2, icg = blockIdx.z & 3;
  const int tid = threadIdx.x;
  const int posg = tid & 31;
  const int ocg = tid >> 5;
  const int owg = posg & 1, ohl = posg >> 1;
  const int ih0 = ht * 16, iw0 = wt * 32;
  float acc[4][16] = {};

  for (int ch = 0; ch < 4; ++ch) {
    __syncthreads();
    for (int j = tid; j < 2 * 24 * 40; j += 128) {
      const int icl = j / 960, r = (j % 960) / 40, c = j % 40;
      const int ih = min(ih0 + r, 70), iw = min(iw0 + c, 70);
      xs[icl][r][c] =
          x[((size_t)b * 32 + icg * 8 + ch * 2 + icl) * 5041 + ih * 71 + iw];
    }
    __syncthreads();
    for (int icl = 0; icl < 2; ++icl) {
      const int ic = icg * 8 + ch * 2 + icl;
      for (int kh = 0; kh < 9; ++kh) {
        float xv[24];
        const float* xr = &xs[icl][ohl + kh][owg * 16];
        #pragma unroll
        for (int j = 0; j < 6; ++j) *(float4*)&xv[4 * j] = *(const float4*)&xr[4 * j];
        float wv[4][9];
        #pragma unroll
        for (int o = 0; o < 4; ++o) {
          const float* wr = &wT[((ic * 9 + kh) * 16 + ocg * 4 + o) * 12];
          *(float4*)&wv[o][0] = *(const float4*)&wr[0];
          *(float4*)&wv[o][4] = *(const float4*)&wr[4];
          wv[o][8] = wr[8];
        }
        #pragma unroll
        for (int kw = 0; kw < 9; ++kw)
          #pragma unroll
          for (int o = 0; o < 4; ++o)
            #pragma unroll
            for (int p = 0; p < 16; ++p)
              acc[o][p] += xv[kw + p] * wv[o][kw];
      }
    }
  }

  const int oh = ih0 + ohl;
  if (oh >= 63) return;
  const int ow0 = iw0 + owg * 16;
  float* pp = part + (size_t)icg * 2032128;
  #pragma unroll
  for (int o = 0; o < 4; ++o) {
    const int oc = ocg * 4 + o;
    float* op = &pp[(((size_t)b * 16 + oc) * 63 + oh) * 63 + ow0];
    #pragma unroll
    for (int p = 0; p < 16; ++p)
      if (ow0 + p < 63) op[p] = acc[o][p];
  }
}

// ---------------- combineT: sum nicg partials + bias + relu, output TRANSPOSED
// part layout: [icg][b][16oc][npos]; outT layout: [oc][pos][b32].
__global__ __launch_bounds__(256) void combineT(const float* __restrict__ part,
                                                const float* __restrict__ bias,
                                                float* __restrict__ outT,
                                                int npos, int total, int nicg,
                                                int bias_pp) {
  __shared__ float tile[64][33];
  const int oc = blockIdx.x;
  const int pos0 = blockIdx.y * 64;
  const int tid = threadIdx.x;
  for (int j = tid; j < 2048; j += 256) {
    const int pl = j & 63;
    const int b = j >> 6;
    const int pos = min(pos0 + pl, npos - 1);
    const size_t idx = ((size_t)b * 16 + oc) * npos + pos;
    float v = 0.f;
    for (int g = 0; g < nicg; ++g) v += part[idx + (size_t)g * total];
    v += bias_pp ? bias[oc * npos + pos] : bias[oc];
    tile[pl][b] = fmaxf(v, 0.f);
  }
  __syncthreads();
  for (int j = tid; j < 2048; j += 256) {
    const int b = j & 31;
    const int pl = j >> 5;
    const int pos = pos0 + pl;
    if (pos < npos) outT[((size_t)oc * npos + pos) * 32 + b] = tile[pl][b];
  }
}

// ---------------- local conv v8: NO LDS. x pre-transposed to [ic][pos][b32].
template <int KH, int S, int IH, int OH>
__global__ __launch_bounds__(256, 4) void lc_v8(const float* __restrict__ xt,
                                                const float* __restrict__ w,
                                                float* __restrict__ part) {
  constexpr int KHW = KH * KH;
  constexpr int NPOS = OH * OH;
  constexpr int WOC = 16 * KHW;
  constexpr int KC4 = KHW / 4;               // 20 / 12 / 6
  const int tid = threadIdx.x;
  const int lane = tid & 63, wvi = tid >> 6;
  const int p = lane >> 4;
  const int og = (lane >> 3) & 1;
  const int bg = lane & 7;
  int mypos = blockIdx.x * 16 + wvi * 4 + p;
  if (mypos >= NPOS) mypos = NPOS - 1;
  const int icg = blockIdx.y;
  const int oh = mypos / OH, ow = mypos % OH;

  float acc[8][4] = {};
  #pragma unroll 1
  for (int ics = 0; ics < 2; ++ics) {
    const int ic = icg * 2 + ics;
    const float* wic = w + ((size_t)mypos * 16 + og * 8) * WOC + (size_t)ic * KHW;
    const float* xic =
        xt + (((size_t)ic * IH + oh * S) * IH + ow * S) * 32 + bg * 4;
    #pragma unroll 1
    for (int kc = 0; kc < KC4; ++kc) {
      float4 wf[8];
      #pragma unroll
      for (int o = 0; o < 8; ++o)
        wf[o] = *(const float4*)&wic[o * WOC + kc * 4];
      float4 xv[4];
      #pragma unroll
      for (int kk = 0; kk < 4; ++kk) {
        const int k = kc * 4 + kk;
        const int kh = k / KH, kw = k - kh * KH;
        xv[kk] = *(const float4*)&xic[(kh * IH + kw) * 32];
      }
      #pragma unroll
      for (int kk = 0; kk < 4; ++kk) {
        const float4 xk = xv[kk];
        #pragma unroll
        for (int o = 0; o < 8; ++o) {
          const float wv = (kk == 0) ? wf[o].x
                         : (kk == 1) ? wf[o].y
                         : (kk == 2) ? wf[o].z
                                     : wf[o].w;
          acc[o][0] += wv * xk.x;
          acc[o][1] += wv * xk.y;
          acc[o][2] += wv * xk.z;
          acc[o][3] += wv * xk.w;
        }
      }
    }
    {  // tail k = KHW-1
      const int k = KHW - 1;
      const float4 xk = *(const float4*)&xic[((KH - 1) * IH + (KH - 1)) * 32];
      #pragma unroll
      for (int o = 0; o < 8; ++o) {
        const float wv = wic[o * WOC + k];
        acc[o][0] += wv * xk.x;
        acc[o][1] += wv * xk.y;
        acc[o][2] += wv * xk.z;
        acc[o][3] += wv * xk.w;
      }
    }
  }

  float* pp = part + (size_t)icg * (32 * 16 * NPOS);
  #pragma unroll
  for (int o = 0; o < 8; ++o) {
    const int oc = og * 8 + o;
    #pragma unroll
    for (int i = 0; i < 4; ++i) {
      const int b = bg * 4 + i;
      pp[(((size_t)b * 16 + oc) * OH + oh) * OH + ow] = acc[o][i];
    }
  }
}

// ---------------- fc1: reg-tiled GEMM; xt = h5T ([oc][pos][b] == [k][b])
__global__ __launch_bounds__(256) void fc1_v2(const float* __restrict__ xt,
                                              const float* __restrict__ w,
                                              const float* __restrict__ bias,
                                              float* __restrict__ out) {
  const int lane = threadIdx.x & 63;
  const int b0 = (threadIdx.x >> 6) * 8;
  const int n0 = blockIdx.x * 8;
  float acc[8][8] = {};
  for (int it = 0; it < 28; ++it) {
    const int kb = it * 256 + lane * 4;
    float4 wf[8], xa[4], xb[4];
    if (kb < 7056) {
      #pragma unroll
      for (int n = 0; n < 8; ++n)
        wf[n] = *(const float4*)&w[(size_t)(n0 + n) * 7056 + kb];
      #pragma unroll
      for (int j = 0; j < 4; ++j) {
        xa[j] = *(const float4*)&xt[(size_t)(kb + j) * 32 + b0];
        xb[j] = *(const float4*)&xt[(size_t)(kb + j) * 32 + b0 + 4];
      }
    } else {
      #pragma unroll
      for (int n = 0; n < 8; ++n) wf[n] = make_float4(0.f, 0.f, 0.f, 0.f);
      #pragma unroll
      for (int j = 0; j < 4; ++j) {
        xa[j] = make_float4(0.f, 0.f, 0.f, 0.f);
        xb[j] = make_float4(0.f, 0.f, 0.f, 0.f);
      }
    }
    #pragma unroll
    for (int n = 0; n < 8; ++n) {
      const float wk[4] = {wf[n].x, wf[n].y, wf[n].z, wf[n].w};
      #pragma unroll
      for (int j = 0; j < 4; ++j) {
        acc[n][0] += wk[j] * xa[j].x;
        acc[n][1] += wk[j] * xa[j].y;
        acc[n][2] += wk[j] * xa[j].z;
        acc[n][3] += wk[j] * xa[j].w;
        acc[n][4] += wk[j] * xb[j].x;
        acc[n][5] += wk[j] * xb[j].y;
        acc[n][6] += wk[j] * xb[j].z;
        acc[n][7] += wk[j] * xb[j].w;
      }
    }
  }
  #pragma unroll
  for (int n = 0; n < 8; ++n)
    #pragma unroll
    for (int c = 0; c < 8; ++c)
      #pragma unroll
      for (int m = 1; m < 64; m <<= 1)
        acc[n][c] += __shfl_xor(acc[n][c], m, 64);
  float val = 0.f;
  #pragma unroll
  for (int n = 0; n < 8; ++n)
    #pragma unroll
    for (int c = 0; c < 8; ++c)
      if (lane == n * 8 + c) val = acc[n][c];
  const int n_l = lane >> 3, b_l = lane & 7;
  out[(size_t)(b0 + b_l) * 4096 + n0 + n_l] = val + bias[n0 + n_l];
}

extern "C" void kernel_launch(void* const* d_in, const int* in_sizes, int n_in,
                              void* d_out, int out_size, void* d_ws, size_t ws_size,
                              hipStream_t stream) {
  const float* x       = (const float*)d_in[0];
  const float* conv1_w = (const float*)d_in[1];
  const float* conv1_b = (const float*)d_in[2];
  const float* conv2_w = (const float*)d_in[3];
  const float* conv2_b = (const float*)d_in[4];
  const float* lc1_w   = (const float*)d_in[5];
  const float* lc1_b   = (const float*)d_in[6];
  const float* lc2_w   = (const float*)d_in[7];
  const float* lc2_b   = (const float*)d_in[8];
  const float* lc3_w   = (const float*)d_in[9];
  const float* lc3_b   = (const float*)d_in[10];
  const float* fc1_w   = (const float*)d_in[11];
  const float* fc1_b   = (const float*)d_in[12];
  float* out = (float*)d_out;
  char* ws = (char*)d_ws;

  // layout (bytes):
  float* h1  = (float*)(ws + 0);           // 32*32*142*142      82,591,744 (dead after pool)
  float* p1  = (float*)(ws + 82591744);    // 32*32*71*71        20,647,936 (dead after conv2_part)
  float* h2T = (float*)(ws + 103239680);   // 16*3969*32          8,128,512
  float* h3T = (float*)(ws + 0);           // 16*3025*32          6,195,200
  float* h4T = (float*)(ws + 8388608);     // 16*625*32           1,280,000
  float* h5T = (float*)(ws + 16777216);    // 16*441*32             903,168
  float* c2p = (float*)(ws + 41943040);    // 4*32*16*3969       32,514,048 (dead after its combineT)
  float* lcp = (float*)(ws + 41943040);    // 8*32*16*3025 max   49,561,600 (reused per lc layer)
  // wT1 lives in p1's slot (only needed during conv1, before pool writes p1):
  float* wT1 = (float*)(ws + 82591744);    // 33*32*12 = 50,688 B
  // wT2 written after pool (h1 dead), beyond c2p end, before lc1 reuses lcp:
  float* wT2 = (float*)(ws + 74457088);    // 32*9*16*12 = 221,184 B

  prep_w1<<<50, 256, 0, stream>>>(conv1_w, wT1);
  conv1_v4<<<dim3(5, 9, 32), 256, 0, stream>>>(x, wT1, conv1_b, h1);
  pool_3_2_1<<<20164, 256, 0, stream>>>(h1, p1);
  prep_w2<<<216, 256, 0, stream>>>(conv2_w, wT2);
  conv2_part<<<dim3(2, 4, 128), 128, 0, stream>>>(p1, wT2, c2p);
  combineT<<<dim3(16, 63), 256, 0, stream>>>(c2p, conv2_b, h2T, 3969, 2032128, 4, 0);

  lc_v8<9, 1, 63, 55><<<dim3(190, 8), 256, 0, stream>>>(h2T, lc1_w, lcp);
  combineT<<<dim3(16, 48), 256, 0, stream>>>(lcp, lc1_b, h3T, 3025, 1548800, 8, 1);
  lc_v8<7, 2, 55, 25><<<dim3(40, 8), 256, 0, stream>>>(h3T, lc2_w, lcp);
  combineT<<<dim3(16, 10), 256, 0, stream>>>(lcp, lc2_b, h4T, 625, 320000, 8, 1);
  lc_v8<5, 1, 25, 21><<<dim3(28, 8), 256, 0, stream>>>(h4T, lc3_w, lcp);
  combineT<<<dim3(16, 7), 256, 0, stream>>>(lcp, lc3_b, h5T, 441, 225792, 8, 1);

  fc1_v2<<<512, 256, 0, stream>>>(h5T, fc1_w, fc1_b, out);
}

// Round 10
// 978.340 us; speedup vs baseline: 1.0343x; 1.0343x over previous
//
#include <hip/hip_runtime.h>
#include <cstddef>

// ---------------- weight prep: conv1 w (32,3,11,11) -> wT1 [r=ic*11+kh][oc][12]
__global__ __launch_bounds__(256) void prep_w1(const float* __restrict__ w,
                                               float* __restrict__ wT) {
  const int j = blockIdx.x * 256 + threadIdx.x;
  if (j >= 33 * 32 * 12) return;
  const int kw = j % 12, oc = (j / 12) % 32, r = j / (12 * 32);
  wT[j] = (kw < 11) ? w[oc * 363 + r * 11 + kw] : 0.f;
}

// ---------------- weight prep: conv2 w (16,32,9,9) -> wT2b [ic][oc][84]
__global__ __launch_bounds__(256) void prep_w2b(const float* __restrict__ w,
                                                float* __restrict__ wT) {
  const int j = blockIdx.x * 256 + threadIdx.x;
  if (j >= 32 * 16 * 84) return;
  const int kp = j % 84, oc = (j / 84) % 16, ic = j / (84 * 16);
  wT[j] = (kp < 81) ? w[(size_t)oc * 2592 + ic * 81 + kp] : 0.f;
}

// ---------------- conv1 v4: weights direct from global wT1 (broadcast, L2-hot)
__global__ __launch_bounds__(256, 4) void conv1_v4(const float* __restrict__ x,
                                                   const float* __restrict__ wT,
                                                   const float* __restrict__ bias,
                                                   float* __restrict__ out) {
  __shared__ __align__(16) float xs[3][26][44];
  const int wt = blockIdx.x, ht = blockIdx.y, b = blockIdx.z;
  const int tid = threadIdx.x;
  const int posg = tid & 31;
  const int ocg = tid >> 5;
  const int owg = posg & 1;
  const int ohl = posg >> 1;
  const int ih0 = ht * 16, iw0 = wt * 32;

  for (int j = tid; j < 3 * 26 * 42; j += 256) {
    const int ic = j / 1092, r = (j % 1092) / 42, c = j % 42;
    const int ih = min(ih0 + r, 151), iw = min(iw0 + c, 151);
    xs[ic][r][c] = x[((size_t)b * 3 + ic) * 23104 + ih * 152 + iw];
  }
  __syncthreads();

  const int oh = ih0 + ohl;
  if (oh >= 142) return;
  float acc[4][16] = {};
  for (int ic = 0; ic < 3; ++ic) {
    for (int kh = 0; kh < 11; ++kh) {
      const int r = ic * 11 + kh;
      float xv[28];
      const float* xr = &xs[ic][ohl + kh][owg * 16];
      #pragma unroll
      for (int j = 0; j < 7; ++j) *(float4*)&xv[4 * j] = *(const float4*)&xr[4 * j];
      float wv[4][12];
      #pragma unroll
      for (int o = 0; o < 4; ++o) {
        const float* wr = &wT[(r * 32 + ocg * 4 + o) * 12];
        *(float4*)&wv[o][0] = *(const float4*)&wr[0];
        *(float4*)&wv[o][4] = *(const float4*)&wr[4];
        *(float4*)&wv[o][8] = *(const float4*)&wr[8];
      }
      #pragma unroll
      for (int kw = 0; kw < 11; ++kw)
        #pragma unroll
        for (int o = 0; o < 4; ++o)
          #pragma unroll
          for (int p = 0; p < 16; ++p)
            acc[o][p] += xv[kw + p] * wv[o][kw];
    }
  }

  const int ow0 = iw0 + owg * 16;
  #pragma unroll
  for (int o = 0; o < 4; ++o) {
    const int oc = ocg * 4 + o;
    const float bv = bias[oc];
    float* op = &out[(((size_t)b * 32 + oc) * 142 + oh) * 142 + ow0];
    if (ow0 + 16 <= 142) {
      #pragma unroll
      for (int p = 0; p < 16; p += 2) {
        float2 rv;
        rv.x = fmaxf(acc[o][p] + bv, 0.f);
        rv.y = fmaxf(acc[o][p + 1] + bv, 0.f);
        *(float2*)&op[p] = rv;
      }
    } else {
      for (int p = 0; p < 16; ++p)
        if (ow0 + p < 142) op[p] = fmaxf(acc[o][p] + bv, 0.f);
    }
  }
}

// ---------------- maxpool 3x3 s2 p1
__global__ __launch_bounds__(256) void pool_3_2_1(const float* __restrict__ in,
                                                  float* __restrict__ out) {
  const int idx = blockIdx.x * 256 + threadIdx.x;
  const int total = 32 * 32 * 71 * 71;
  if (idx >= total) return;
  const int ow = idx % 71;
  const int oh = (idx / 71) % 71;
  const int bc = idx / (71 * 71);
  const float* base = in + (size_t)bc * 142 * 142;
  float m = -1e30f;
  #pragma unroll
  for (int kh = 0; kh < 3; ++kh) {
    const int ih = oh * 2 - 1 + kh;
    if (ih < 0 || ih >= 142) continue;
    #pragma unroll
    for (int kw = 0; kw < 3; ++kw) {
      const int iw = ow * 2 - 1 + kw;
      if (iw < 0 || iw >= 142) continue;
      m = fmaxf(m, base[ih * 142 + iw]);
    }
  }
  out[idx] = m;
}

// ---------------- transpose p1 (b,c,71,71) -> p1T [c][pos 5041][b32]
__global__ __launch_bounds__(256) void t_p1(const float* __restrict__ in,
                                            float* __restrict__ outT) {
  __shared__ float tile[64][33];
  const int c = blockIdx.x;
  const int pos0 = blockIdx.y * 64;
  const int tid = threadIdx.x;
  for (int j = tid; j < 2048; j += 256) {
    const int pl = j & 63;
    const int b = j >> 6;
    const int pos = min(pos0 + pl, 5040);
    tile[pl][b] = in[((size_t)b * 32 + c) * 5041 + pos];
  }
  __syncthreads();
  for (int j = tid; j < 2048; j += 256) {
    const int b = j & 31;
    const int pl = j >> 5;
    const int pos = pos0 + pl;
    if (pos < 5041) outT[((size_t)c * 5041 + pos) * 32 + b] = tile[pl][b];
  }
}

// ---------------- conv2 v4: lc_v8-style. NO LDS, NO barriers.
// x from p1T [ic][5041][b32]; w from wT2b [ic][oc][84] (broadcast).
// Wave = 4 pos x 2 og x 8 bg; thread = 8 oc x 4 b; ic-split x4 (8 ic each).
__global__ __launch_bounds__(256, 4) void conv2_v4(const float* __restrict__ xt,
                                                   const float* __restrict__ wT,
                                                   float* __restrict__ part) {
  const int tid = threadIdx.x;
  const int lane = tid & 63, wvi = tid >> 6;
  const int p = lane >> 4;
  const int og = (lane >> 3) & 1;
  const int bg = lane & 7;
  int mypos = blockIdx.x * 16 + wvi * 4 + p;
  if (mypos >= 3969) mypos = 3968;
  const int icg = blockIdx.y;                // 0..3, 8 ic each
  const int oh = mypos / 63, ow = mypos % 63;

  float acc[8][4] = {};
  #pragma unroll 1
  for (int ics = 0; ics < 8; ++ics) {
    const int ic = icg * 8 + ics;
    const float* wic = wT + ((size_t)ic * 16 + og * 8) * 84;
    const float* xic = xt + ((size_t)ic * 5041 + oh * 71 + ow) * 32 + bg * 4;
    #pragma unroll 1
    for (int kc = 0; kc < 20; ++kc) {
      float4 wf[8];
      #pragma unroll
      for (int o = 0; o < 8; ++o)
        wf[o] = *(const float4*)&wic[o * 84 + kc * 4];
      float4 xv[4];
      #pragma unroll
      for (int kk = 0; kk < 4; ++kk) {
        const int k = kc * 4 + kk;
        const int kh = k / 9, kw = k - kh * 9;
        xv[kk] = *(const float4*)&xic[(kh * 71 + kw) * 32];
      }
      #pragma unroll
      for (int kk = 0; kk < 4; ++kk) {
        const float4 xk = xv[kk];
        #pragma unroll
        for (int o = 0; o < 8; ++o) {
          const float wv = (kk == 0) ? wf[o].x
                         : (kk == 1) ? wf[o].y
                         : (kk == 2) ? wf[o].z
                                     : wf[o].w;
          acc[o][0] += wv * xk.x;
          acc[o][1] += wv * xk.y;
          acc[o][2] += wv * xk.z;
          acc[o][3] += wv * xk.w;
        }
      }
    }
    {  // tail k = 80 (kh=8, kw=8)
      const float4 xk = *(const float4*)&xic[(8 * 71 + 8) * 32];
      #pragma unroll
      for (int o = 0; o < 8; ++o) {
        const float wv = wic[o * 84 + 80];
        acc[o][0] += wv * xk.x;
        acc[o][1] += wv * xk.y;
        acc[o][2] += wv * xk.z;
        acc[o][3] += wv * xk.w;
      }
    }
  }

  float* pp = part + (size_t)icg * 2032128;
  #pragma unroll
  for (int o = 0; o < 8; ++o) {
    const int oc = og * 8 + o;
    #pragma unroll
    for (int i = 0; i < 4; ++i) {
      const int b = bg * 4 + i;
      pp[(((size_t)b * 16 + oc) * 63 + oh) * 63 + ow] = acc[o][i];
    }
  }
}

// ---------------- combineT: sum nicg partials + bias + relu, output TRANSPOSED
__global__ __launch_bounds__(256) void combineT(const float* __restrict__ part,
                                                const float* __restrict__ bias,
                                                float* __restrict__ outT,
                                                int npos, int total, int nicg,
                                                int bias_pp) {
  __shared__ float tile[64][33];
  const int oc = blockIdx.x;
  const int pos0 = blockIdx.y * 64;
  const int tid = threadIdx.x;
  for (int j = tid; j < 2048; j += 256) {
    const int pl = j & 63;
    const int b = j >> 6;
    const int pos = min(pos0 + pl, npos - 1);
    const size_t idx = ((size_t)b * 16 + oc) * npos + pos;
    float v = 0.f;
    for (int g = 0; g < nicg; ++g) v += part[idx + (size_t)g * total];
    v += bias_pp ? bias[oc * npos + pos] : bias[oc];
    tile[pl][b] = fmaxf(v, 0.f);
  }
  __syncthreads();
  for (int j = tid; j < 2048; j += 256) {
    const int b = j & 31;
    const int pl = j >> 5;
    const int pos = pos0 + pl;
    if (pos < npos) outT[((size_t)oc * npos + pos) * 32 + b] = tile[pl][b];
  }
}

// ---------------- local conv v8: NO LDS. x pre-transposed to [ic][pos][b32].
template <int KH, int S, int IH, int OH>
__global__ __launch_bounds__(256, 4) void lc_v8(const float* __restrict__ xt,
                                                const float* __restrict__ w,
                                                float* __restrict__ part) {
  constexpr int KHW = KH * KH;
  constexpr int NPOS = OH * OH;
  constexpr int WOC = 16 * KHW;
  constexpr int KC4 = KHW / 4;               // 20 / 12 / 6
  const int tid = threadIdx.x;
  const int lane = tid & 63, wvi = tid >> 6;
  const int p = lane >> 4;
  const int og = (lane >> 3) & 1;
  const int bg = lane & 7;
  int mypos = blockIdx.x * 16 + wvi * 4 + p;
  if (mypos >= NPOS) mypos = NPOS - 1;
  const int icg = blockIdx.y;
  const int oh = mypos / OH, ow = mypos % OH;

  float acc[8][4] = {};
  #pragma unroll 1
  for (int ics = 0; ics < 2; ++ics) {
    const int ic = icg * 2 + ics;
    const float* wic = w + ((size_t)mypos * 16 + og * 8) * WOC + (size_t)ic * KHW;
    const float* xic =
        xt + (((size_t)ic * IH + oh * S) * IH + ow * S) * 32 + bg * 4;
    #pragma unroll 1
    for (int kc = 0; kc < KC4; ++kc) {
      float4 wf[8];
      #pragma unroll
      for (int o = 0; o < 8; ++o)
        wf[o] = *(const float4*)&wic[o * WOC + kc * 4];
      float4 xv[4];
      #pragma unroll
      for (int kk = 0; kk < 4; ++kk) {
        const int k = kc * 4 + kk;
        const int kh = k / KH, kw = k - kh * KH;
        xv[kk] = *(const float4*)&xic[(kh * IH + kw) * 32];
      }
      #pragma unroll
      for (int kk = 0; kk < 4; ++kk) {
        const float4 xk = xv[kk];
        #pragma unroll
        for (int o = 0; o < 8; ++o) {
          const float wv = (kk == 0) ? wf[o].x
                         : (kk == 1) ? wf[o].y
                         : (kk == 2) ? wf[o].z
                                     : wf[o].w;
          acc[o][0] += wv * xk.x;
          acc[o][1] += wv * xk.y;
          acc[o][2] += wv * xk.z;
          acc[o][3] += wv * xk.w;
        }
      }
    }
    {  // tail k = KHW-1
      const int k = KHW - 1;
      const float4 xk = *(const float4*)&xic[((KH - 1) * IH + (KH - 1)) * 32];
      #pragma unroll
      for (int o = 0; o < 8; ++o) {
        const float wv = wic[o * WOC + k];
        acc[o][0] += wv * xk.x;
        acc[o][1] += wv * xk.y;
        acc[o][2] += wv * xk.z;
        acc[o][3] += wv * xk.w;
      }
    }
  }

  float* pp = part + (size_t)icg * (32 * 16 * NPOS);
  #pragma unroll
  for (int o = 0; o < 8; ++o) {
    const int oc = og * 8 + o;
    #pragma unroll
    for (int i = 0; i < 4; ++i) {
      const int b = bg * 4 + i;
      pp[(((size_t)b * 16 + oc) * OH + oh) * OH + ow] = acc[o][i];
    }
  }
}

// ---------------- fc1: reg-tiled GEMM; xt = h5T ([oc][pos][b] == [k][b])
__global__ __launch_bounds__(256) void fc1_v2(const float* __restrict__ xt,
                                              const float* __restrict__ w,
                                              const float* __restrict__ bias,
                                              float* __restrict__ out) {
  const int lane = threadIdx.x & 63;
  const int b0 = (threadIdx.x >> 6) * 8;
  const int n0 = blockIdx.x * 8;
  float acc[8][8] = {};
  for (int it = 0; it < 28; ++it) {
    const int kb = it * 256 + lane * 4;
    float4 wf[8], xa[4], xb[4];
    if (kb < 7056) {
      #pragma unroll
      for (int n = 0; n < 8; ++n)
        wf[n] = *(const float4*)&w[(size_t)(n0 + n) * 7056 + kb];
      #pragma unroll
      for (int j = 0; j < 4; ++j) {
        xa[j] = *(const float4*)&xt[(size_t)(kb + j) * 32 + b0];
        xb[j] = *(const float4*)&xt[(size_t)(kb + j) * 32 + b0 + 4];
      }
    } else {
      #pragma unroll
      for (int n = 0; n < 8; ++n) wf[n] = make_float4(0.f, 0.f, 0.f, 0.f);
      #pragma unroll
      for (int j = 0; j < 4; ++j) {
        xa[j] = make_float4(0.f, 0.f, 0.f, 0.f);
        xb[j] = make_float4(0.f, 0.f, 0.f, 0.f);
      }
    }
    #pragma unroll
    for (int n = 0; n < 8; ++n) {
      const float wk[4] = {wf[n].x, wf[n].y, wf[n].z, wf[n].w};
      #pragma unroll
      for (int j = 0; j < 4; ++j) {
        acc[n][0] += wk[j] * xa[j].x;
        acc[n][1] += wk[j] * xa[j].y;
        acc[n][2] += wk[j] * xa[j].z;
        acc[n][3] += wk[j] * xa[j].w;
        acc[n][4] += wk[j] * xb[j].x;
        acc[n][5] += wk[j] * xb[j].y;
        acc[n][6] += wk[j] * xb[j].z;
        acc[n][7] += wk[j] * xb[j].w;
      }
    }
  }
  #pragma unroll
  for (int n = 0; n < 8; ++n)
    #pragma unroll
    for (int c = 0; c < 8; ++c)
      #pragma unroll
      for (int m = 1; m < 64; m <<= 1)
        acc[n][c] += __shfl_xor(acc[n][c], m, 64);
  float val = 0.f;
  #pragma unroll
  for (int n = 0; n < 8; ++n)
    #pragma unroll
    for (int c = 0; c < 8; ++c)
      if (lane == n * 8 + c) val = acc[n][c];
  const int n_l = lane >> 3, b_l = lane & 7;
  out[(size_t)(b0 + b_l) * 4096 + n0 + n_l] = val + bias[n0 + n_l];
}

extern "C" void kernel_launch(void* const* d_in, const int* in_sizes, int n_in,
                              void* d_out, int out_size, void* d_ws, size_t ws_size,
                              hipStream_t stream) {
  const float* x       = (const float*)d_in[0];
  const float* conv1_w = (const float*)d_in[1];
  const float* conv1_b = (const float*)d_in[2];
  const float* conv2_w = (const float*)d_in[3];
  const float* conv2_b = (const float*)d_in[4];
  const float* lc1_w   = (const float*)d_in[5];
  const float* lc1_b   = (const float*)d_in[6];
  const float* lc2_w   = (const float*)d_in[7];
  const float* lc2_b   = (const float*)d_in[8];
  const float* lc3_w   = (const float*)d_in[9];
  const float* lc3_b   = (const float*)d_in[10];
  const float* fc1_w   = (const float*)d_in[11];
  const float* fc1_b   = (const float*)d_in[12];
  float* out = (float*)d_out;
  char* ws = (char*)d_ws;

  // timeline-aware layout (bytes), budget ~111.4 MB:
  float* h1   = (float*)(ws + 0);          // 82,591,744 (live: conv1->pool)
  float* p1   = (float*)(ws + 82591744);   // 20,647,936 (live: pool->t_p1)
  float* wT1  = (float*)(ws + 82591744);   // 50,688 (live during conv1 only; before pool writes p1... NOTE: overlaps p1)
  float* p1T  = (float*)(ws + 0);          // 20,647,936 (written after pool; h1 dead)
  float* wT2  = (float*)(ws + 20971520);   // 172,032 (after p1T, before c2p)
  float* c2p  = (float*)(ws + 41943040);   // 32,514,048 (conv2 partials; dead after combineT)
  float* h2T  = (float*)(ws + 103239680);  //  8,128,512
  float* h3T  = (float*)(ws + 0);          //  6,195,200 (p1T dead by lc1-combine)
  float* h4T  = (float*)(ws + 8388608);    //  1,280,000
  float* h5T  = (float*)(ws + 16777216);   //    903,168
  float* lcp  = (float*)(ws + 41943040);   // 49,561,600 (lc partials)

  prep_w1<<<50, 256, 0, stream>>>(conv1_w, wT1);
  conv1_v4<<<dim3(5, 9, 32), 256, 0, stream>>>(x, wT1, conv1_b, h1);
  pool_3_2_1<<<20164, 256, 0, stream>>>(h1, p1);         // overwrites wT1 (dead)
  t_p1<<<dim3(32, 79), 256, 0, stream>>>(p1, p1T);       // h1 dead -> p1T at 0
  prep_w2b<<<168, 256, 0, stream>>>(conv2_w, wT2);
  conv2_v4<<<dim3(249, 4), 256, 0, stream>>>(p1T, wT2, c2p);
  combineT<<<dim3(16, 63), 256, 0, stream>>>(c2p, conv2_b, h2T, 3969, 2032128, 4, 0);

  lc_v8<9, 1, 63, 55><<<dim3(190, 8), 256, 0, stream>>>(h2T, lc1_w, lcp);
  combineT<<<dim3(16, 48), 256, 0, stream>>>(lcp, lc1_b, h3T, 3025, 1548800, 8, 1);
  lc_v8<7, 2, 55, 25><<<dim3(40, 8), 256, 0, stream>>>(h3T, lc2_w, lcp);
  combineT<<<dim3(16, 10), 256, 0, stream>>>(lcp, lc2_b, h4T, 625, 320000, 8, 1);
  lc_v8<5, 1, 25, 21><<<dim3(28, 8), 256, 0, stream>>>(h4T, lc3_w, lcp);
  combineT<<<dim3(16, 7), 256, 0, stream>>>(lcp, lc3_b, h5T, 441, 225792, 8, 1);

  fc1_v2<<<512, 256, 0, stream>>>(h5T, fc1_w, fc1_b, out);
}